// Round 1
// baseline (1446.114 us; speedup 1.0000x reference)
//
#include <hip/hip_runtime.h>

#define NFEAT 128
#define GROWS 16

// ---------------- degree count: cnt[col[e]] += 1 ----------------
__global__ void count_deg_kernel(const int* __restrict__ col, int E,
                                 unsigned int* __restrict__ cnt) {
    int i = blockIdx.x * blockDim.x + threadIdx.x;
    if (i < E) atomicAdd(&cnt[col[i]], 1u);
}

// ---------------- dinv[i] = rsqrt(cnt[i] + 1)  (self-loop) ----------------
__global__ void dinv_kernel(const unsigned int* __restrict__ cnt,
                            float* __restrict__ dinv, int N) {
    int i = blockIdx.x * blockDim.x + threadIdx.x;
    if (i < N) dinv[i] = rsqrtf((float)(cnt[i] + 1u));
}

// ---------------- h = x @ W  (N x 128) @ (128 x 128), fp32 vector ----------------
// 128 threads/block, each thread owns one output column c for GROWS rows.
__global__ void gemm_kernel(const float* __restrict__ x, const float* __restrict__ W,
                            float* __restrict__ h, int N) {
    __shared__ float xs[GROWS][NFEAT];
    int c = threadIdx.x;              // 0..127
    int r0 = blockIdx.x * GROWS;
    for (int j = 0; j < GROWS; ++j) {
        int r = r0 + j;
        xs[j][c] = (r < N) ? x[(size_t)r * NFEAT + c] : 0.f;
    }
    __syncthreads();
    float acc[GROWS];
    #pragma unroll
    for (int j = 0; j < GROWS; ++j) acc[j] = 0.f;
    #pragma unroll 4
    for (int k = 0; k < NFEAT; ++k) {
        float w = W[k * NFEAT + c];   // coalesced, L1/L2-resident (64 KB)
        #pragma unroll
        for (int j = 0; j < GROWS; ++j) acc[j] += xs[j][k] * w;
    }
    for (int j = 0; j < GROWS; ++j) {
        int r = r0 + j;
        if (r < N) h[(size_t)r * NFEAT + c] = acc[j];
    }
}

// ---------------- scatter: out[col[e]] += h[row[e]] * dinv[row]*dinv[col] ----------------
// 32 lanes per edge, one float4 (4 columns) per lane.
__global__ void scatter_kernel(const float4* __restrict__ h4,
                               const int* __restrict__ row, const int* __restrict__ col,
                               const float* __restrict__ dinv,
                               float* __restrict__ out, int E) {
    long long gid = (long long)blockIdx.x * blockDim.x + threadIdx.x;
    int e = (int)(gid >> 5);
    int lane = (int)(gid & 31);
    if (e >= E) return;
    int r = row[e], c = col[e];
    float nrm = dinv[r] * dinv[c];
    float4 v = h4[(size_t)r * 32 + lane];
    float* dst = out + (size_t)c * NFEAT + lane * 4;
    atomicAdd(dst + 0, v.x * nrm);
    atomicAdd(dst + 1, v.y * nrm);
    atomicAdd(dst + 2, v.z * nrm);
    atomicAdd(dst + 3, v.w * nrm);
}

// ---------------- finalize: out = relu(out + h*dinv^2 + bias) ----------------
__global__ void finalize_kernel(const float4* __restrict__ h4,
                                const float* __restrict__ dinv,
                                const float4* __restrict__ bias4,
                                float4* __restrict__ out4, int N) {
    int gid = blockIdx.x * blockDim.x + threadIdx.x;
    int i = gid >> 5;
    int lane = gid & 31;
    if (i >= N) return;
    float d = dinv[i];
    float s = d * d;
    float4 o = out4[(size_t)i * 32 + lane];
    float4 hv = h4[(size_t)i * 32 + lane];
    float4 b = bias4[lane];
    float4 rlt;
    rlt.x = fmaxf(o.x + hv.x * s + b.x, 0.f);
    rlt.y = fmaxf(o.y + hv.y * s + b.y, 0.f);
    rlt.z = fmaxf(o.z + hv.z * s + b.z, 0.f);
    rlt.w = fmaxf(o.w + hv.w * s + b.w, 0.f);
    out4[(size_t)i * 32 + lane] = rlt;
}

extern "C" void kernel_launch(void* const* d_in, const int* in_sizes, int n_in,
                              void* d_out, int out_size, void* d_ws, size_t ws_size,
                              hipStream_t stream) {
    const float* x    = (const float*)d_in[0];
    const int*   ei   = (const int*)d_in[1];   // int32 per harness convention
    const float* W    = (const float*)d_in[2];
    const float* bias = (const float*)d_in[3];
    float* out = (float*)d_out;

    int N = in_sizes[0] / NFEAT;   // 50000
    int E = in_sizes[1] / 2;       // 800000
    const int* row = ei;           // edge_index[0]
    const int* col = ei + E;       // edge_index[1]

    // workspace layout: cnt[N] u32 | dinv[N] f32 | h[N*128] f32  (~26 MB)
    char* ws = (char*)d_ws;
    unsigned int* cnt = (unsigned int*)ws;
    float* dinv = (float*)(ws + (size_t)N * 4);
    float* h    = (float*)(ws + (size_t)N * 8);   // 400000 B offset, 16B-aligned

    hipMemsetAsync(cnt, 0, (size_t)N * 4, stream);
    hipMemsetAsync(out, 0, (size_t)N * NFEAT * 4, stream);

    count_deg_kernel<<<(E + 255) / 256, 256, 0, stream>>>(col, E, cnt);
    dinv_kernel<<<(N + 255) / 256, 256, 0, stream>>>(cnt, dinv, N);
    gemm_kernel<<<(N + GROWS - 1) / GROWS, NFEAT, 0, stream>>>(x, W, h, N);

    long long sthreads = (long long)E * 32;
    scatter_kernel<<<(int)((sthreads + 255) / 256), 256, 0, stream>>>(
        (const float4*)h, row, col, dinv, out, E);

    int fthreads = N * 32;
    finalize_kernel<<<(fthreads + 255) / 256, 256, 0, stream>>>(
        (const float4*)h, dinv, (const float4*)bias, (float4*)out, N);
}

// Round 2
// 197.872 us; speedup vs baseline: 7.3083x; 7.3083x over previous
//
#include <hip/hip_runtime.h>

#define NFEAT 128
#define GROWS 16

// ---------------- degree count: cnt[col[e]] += 1 ----------------
__global__ void count_deg_kernel(const int* __restrict__ col, int E,
                                 unsigned int* __restrict__ cnt) {
    int i = blockIdx.x * blockDim.x + threadIdx.x;
    if (i < E) atomicAdd(&cnt[col[i]], 1u);
}

// ---------------- dinv[i] = rsqrt(cnt[i] + 1)  (self-loop) ----------------
__global__ void dinv_kernel(const unsigned int* __restrict__ cnt,
                            float* __restrict__ dinv, int N) {
    int i = blockIdx.x * blockDim.x + threadIdx.x;
    if (i < N) dinv[i] = rsqrtf((float)(cnt[i] + 1u));
}

// ---------------- scan stage 1: per-256-block exclusive scan + block totals ----
__global__ void scan1_kernel(const unsigned int* __restrict__ cnt, int N,
                             int* __restrict__ offs, unsigned int* __restrict__ partial) {
    __shared__ unsigned int s[256];
    int i = blockIdx.x * 256 + threadIdx.x;
    unsigned int v = (i < N) ? cnt[i] : 0u;
    s[threadIdx.x] = v;
    __syncthreads();
    for (int d = 1; d < 256; d <<= 1) {
        unsigned int t = (threadIdx.x >= d) ? s[threadIdx.x - d] : 0u;
        __syncthreads();
        s[threadIdx.x] += t;
        __syncthreads();
    }
    if (i < N) offs[i] = (int)(s[threadIdx.x] - v);   // exclusive within block
    if (threadIdx.x == 255) partial[blockIdx.x] = s[255];
}

// ---------------- scan stage 2: exclusive scan of block totals (single block) ----
__global__ void scan2_kernel(unsigned int* __restrict__ partial, int nb) {
    __shared__ unsigned int s[256];
    unsigned int v = (threadIdx.x < nb) ? partial[threadIdx.x] : 0u;
    s[threadIdx.x] = v;
    __syncthreads();
    for (int d = 1; d < 256; d <<= 1) {
        unsigned int t = (threadIdx.x >= d) ? s[threadIdx.x - d] : 0u;
        __syncthreads();
        s[threadIdx.x] += t;
        __syncthreads();
    }
    if (threadIdx.x < nb) partial[threadIdx.x] = s[threadIdx.x] - v;  // exclusive
}

// ---------------- scan stage 3: add block offsets ----------------
__global__ void scan3_kernel(int* __restrict__ offs, const unsigned int* __restrict__ partial,
                             int N) {
    int i = blockIdx.x * blockDim.x + threadIdx.x;
    if (i < N) offs[i] += (int)partial[i >> 8];
}

// ---------------- g = (x @ W) * dinv[row] ----------------
__global__ void gemm_scaled_kernel(const float* __restrict__ x, const float* __restrict__ W,
                                   const float* __restrict__ dinv,
                                   float* __restrict__ g, int N) {
    __shared__ float xs[GROWS][NFEAT];
    int c = threadIdx.x;              // 0..127
    int r0 = blockIdx.x * GROWS;
    for (int j = 0; j < GROWS; ++j) {
        int r = r0 + j;
        xs[j][c] = (r < N) ? x[(size_t)r * NFEAT + c] : 0.f;
    }
    __syncthreads();
    float acc[GROWS];
    #pragma unroll
    for (int j = 0; j < GROWS; ++j) acc[j] = 0.f;
    #pragma unroll 4
    for (int k = 0; k < NFEAT; ++k) {
        float w = W[k * NFEAT + c];
        #pragma unroll
        for (int j = 0; j < GROWS; ++j) acc[j] += xs[j][k] * w;
    }
    for (int j = 0; j < GROWS; ++j) {
        int r = r0 + j;
        if (r < N) g[(size_t)r * NFEAT + c] = acc[j] * dinv[r];
    }
}

// ---------------- bucket fill: counting sort by destination ----------------
__global__ void fill_kernel(const int* __restrict__ row, const int* __restrict__ col,
                            const int* __restrict__ offs, unsigned int* __restrict__ fill,
                            int* __restrict__ bucket, int E) {
    int e = blockIdx.x * blockDim.x + threadIdx.x;
    if (e < E) {
        int c = col[e];
        unsigned int p = atomicAdd(&fill[c], 1u);
        bucket[offs[c] + (int)p] = row[e];
    }
}

// ---------------- aggregate: one wave per destination node ----------------
// out[c] = relu(dinv[c] * (sum_{r in bucket(c)} g[r] + g[c]) + bias)
__global__ void aggregate_kernel(const float2* __restrict__ g2,
                                 const int* __restrict__ bucket,
                                 const int* __restrict__ offs,
                                 const unsigned int* __restrict__ cnt,
                                 const float* __restrict__ dinv,
                                 const float2* __restrict__ bias2,
                                 float2* __restrict__ out2, int N) {
    int wid = threadIdx.x >> 6;       // 4 waves / block
    int lane = threadIdx.x & 63;      // each lane owns 2 columns
    int c = blockIdx.x * 4 + wid;
    if (c >= N) return;
    int start = offs[c];
    int end = start + (int)cnt[c];
    float2 acc = g2[(size_t)c * 64 + lane];   // self-loop message
    int j = start;
    for (; j + 4 <= end; j += 4) {
        int r0 = bucket[j], r1 = bucket[j + 1], r2 = bucket[j + 2], r3 = bucket[j + 3];
        float2 v0 = g2[(size_t)r0 * 64 + lane];
        float2 v1 = g2[(size_t)r1 * 64 + lane];
        float2 v2 = g2[(size_t)r2 * 64 + lane];
        float2 v3 = g2[(size_t)r3 * 64 + lane];
        acc.x += (v0.x + v1.x) + (v2.x + v3.x);
        acc.y += (v0.y + v1.y) + (v2.y + v3.y);
    }
    for (; j < end; ++j) {
        int r = bucket[j];
        float2 v = g2[(size_t)r * 64 + lane];
        acc.x += v.x;
        acc.y += v.y;
    }
    float d = dinv[c];
    float2 b = bias2[lane];
    float2 o;
    o.x = fmaxf(acc.x * d + b.x, 0.f);
    o.y = fmaxf(acc.y * d + b.y, 0.f);
    out2[(size_t)c * 64 + lane] = o;
}

extern "C" void kernel_launch(void* const* d_in, const int* in_sizes, int n_in,
                              void* d_out, int out_size, void* d_ws, size_t ws_size,
                              hipStream_t stream) {
    const float* x    = (const float*)d_in[0];
    const int*   ei   = (const int*)d_in[1];
    const float* W    = (const float*)d_in[2];
    const float* bias = (const float*)d_in[3];
    float* out = (float*)d_out;

    int N = in_sizes[0] / NFEAT;   // 50000
    int E = in_sizes[1] / 2;       // 800000
    const int* row = ei;           // sources
    const int* col = ei + E;       // destinations

    // workspace layout (16B-aligned chunks):
    // cnt[N] u32 | dinv[N] f32 | offs[N] i32 | fill[N] u32 | partial[256] u32 | bucket[E] i32 | g[N*128] f32
    char* ws = (char*)d_ws;
    size_t o = 0;
    unsigned int* cnt     = (unsigned int*)(ws + o); o += (size_t)N * 4;
    float*        dinv    = (float*)(ws + o);        o += (size_t)N * 4;
    int*          offs    = (int*)(ws + o);          o += (size_t)N * 4;
    unsigned int* fill    = (unsigned int*)(ws + o); o += (size_t)N * 4;
    unsigned int* partial = (unsigned int*)(ws + o); o += 1024;
    int*          bucket  = (int*)(ws + o);          o += (size_t)E * 4;
    float*        g       = (float*)(ws + o);        // N*128 floats

    int nb = (N + 255) / 256;   // 196 scan blocks

    hipMemsetAsync(cnt, 0, (size_t)N * 4, stream);
    hipMemsetAsync(fill, 0, (size_t)N * 4, stream);

    count_deg_kernel<<<(E + 255) / 256, 256, 0, stream>>>(col, E, cnt);
    dinv_kernel<<<(N + 255) / 256, 256, 0, stream>>>(cnt, dinv, N);

    scan1_kernel<<<nb, 256, 0, stream>>>(cnt, N, offs, partial);
    scan2_kernel<<<1, 256, 0, stream>>>(partial, nb);
    scan3_kernel<<<(N + 255) / 256, 256, 0, stream>>>(offs, partial, N);

    gemm_scaled_kernel<<<(N + GROWS - 1) / GROWS, NFEAT, 0, stream>>>(x, W, dinv, g, N);

    fill_kernel<<<(E + 255) / 256, 256, 0, stream>>>(row, col, offs, fill, bucket, E);

    aggregate_kernel<<<(N + 3) / 4, 256, 0, stream>>>(
        (const float2*)g, bucket, offs, cnt, dinv, (const float2*)bias, (float2*)out, N);
}

// Round 3
// 155.477 us; speedup vs baseline: 9.3012x; 1.2727x over previous
//
#include <hip/hip_runtime.h>

#define NFEAT 128

typedef __attribute__((ext_vector_type(8))) short short8;    // 8 bf16 (4 VGPRs)
typedef __attribute__((ext_vector_type(4))) float f32x4;     // MFMA accumulator

__device__ inline short f2bf(float f) {
    unsigned u = __builtin_bit_cast(unsigned, f);
    u += 0x7FFFu + ((u >> 16) & 1u);           // round-to-nearest-even
    return (short)(u >> 16);
}
__device__ inline float bf2f(unsigned short u) {
    return __builtin_bit_cast(float, ((unsigned)u) << 16);
}

// ---------------- degree count: cnt[col[e]] += 1 ----------------
__global__ void count_deg_kernel(const int* __restrict__ col, int E,
                                 unsigned int* __restrict__ cnt) {
    int i = blockIdx.x * blockDim.x + threadIdx.x;
    if (i < E) atomicAdd(&cnt[col[i]], 1u);
}

// ---------------- scan stage 1 (+ fused dinv) ----------------
__global__ void scan1_kernel(const unsigned int* __restrict__ cnt, int N,
                             int* __restrict__ offs, unsigned int* __restrict__ partial,
                             float* __restrict__ dinv) {
    __shared__ unsigned int s[256];
    int i = blockIdx.x * 256 + threadIdx.x;
    unsigned int v = (i < N) ? cnt[i] : 0u;
    if (i < N) dinv[i] = rsqrtf((float)(v + 1u));   // + self-loop
    s[threadIdx.x] = v;
    __syncthreads();
    for (int d = 1; d < 256; d <<= 1) {
        unsigned int t = (threadIdx.x >= d) ? s[threadIdx.x - d] : 0u;
        __syncthreads();
        s[threadIdx.x] += t;
        __syncthreads();
    }
    if (i < N) offs[i] = (int)(s[threadIdx.x] - v);   // exclusive within block
    if (threadIdx.x == 255) partial[blockIdx.x] = s[255];
}

// ---------------- scan stage 2: exclusive scan of block totals ----------------
__global__ void scan2_kernel(unsigned int* __restrict__ partial, int nb) {
    __shared__ unsigned int s[256];
    unsigned int v = (threadIdx.x < nb) ? partial[threadIdx.x] : 0u;
    s[threadIdx.x] = v;
    __syncthreads();
    for (int d = 1; d < 256; d <<= 1) {
        unsigned int t = (threadIdx.x >= d) ? s[threadIdx.x - d] : 0u;
        __syncthreads();
        s[threadIdx.x] += t;
        __syncthreads();
    }
    if (threadIdx.x < nb) partial[threadIdx.x] = s[threadIdx.x] - v;  // exclusive
}

// ---------------- W -> Wt bf16 transposed: Wt[n][k] = bf16(W[k][n]) ----------------
__global__ void wprep_kernel(const float* __restrict__ W, unsigned short* __restrict__ Wt) {
    int i = blockIdx.x * 256 + threadIdx.x;   // 16384
    int k = i >> 7, n = i & 127;
    Wt[n * NFEAT + k] = (unsigned short)f2bf(W[k * NFEAT + n]);
}

// ---------------- g = bf16((x @ W) * dinv[row]) via MFMA ----------------
// 256 threads = 4 waves; each wave computes 16 rows x 128 cols.
__global__ void gemm_mfma_kernel(const float* __restrict__ x,
                                 const unsigned short* __restrict__ Wt,
                                 const float* __restrict__ dinv,
                                 unsigned short* __restrict__ g, int N) {
    int wave = threadIdx.x >> 6;
    int lane = threadIdx.x & 63;
    int li = lane & 15;
    int kg = lane >> 4;                 // 0..3
    int m0 = blockIdx.x * 64 + wave * 16;
    int arow = m0 + li;
    int srow = (arow < N) ? arow : (N - 1);

    f32x4 acc[8];
    #pragma unroll
    for (int nt = 0; nt < 8; ++nt) acc[nt] = (f32x4){0.f, 0.f, 0.f, 0.f};

    #pragma unroll
    for (int ks = 0; ks < 4; ++ks) {
        // A fragment: x[srow][ks*32 + kg*8 + i], converted to bf16
        const float4* xp = (const float4*)(x + (size_t)srow * NFEAT + ks * 32 + kg * 8);
        float4 f0 = xp[0], f1 = xp[1];
        short8 a;
        a[0] = f2bf(f0.x); a[1] = f2bf(f0.y); a[2] = f2bf(f0.z); a[3] = f2bf(f0.w);
        a[4] = f2bf(f1.x); a[5] = f2bf(f1.y); a[6] = f2bf(f1.z); a[7] = f2bf(f1.w);
        #pragma unroll
        for (int nt = 0; nt < 8; ++nt) {
            // B fragment: Wt[nt*16 + li][ks*32 + kg*8 + i]  (same k-mapping as A)
            short8 b = *(const short8*)(Wt + (size_t)(nt * 16 + li) * NFEAT + ks * 32 + kg * 8);
            acc[nt] = __builtin_amdgcn_mfma_f32_16x16x32_bf16(a, b, acc[nt], 0, 0, 0);
        }
    }

    // D layout: col = nt*16 + (lane&15), row = m0 + kg*4 + r   [m89-verified]
    #pragma unroll
    for (int r = 0; r < 4; ++r) {
        int orow = m0 + kg * 4 + r;
        if (orow < N) {
            float dv = dinv[orow];
            unsigned short* gp = g + (size_t)orow * NFEAT + li;
            #pragma unroll
            for (int nt = 0; nt < 8; ++nt)
                gp[nt * 16] = (unsigned short)f2bf(acc[nt][r] * dv);
        }
    }
}

// ---------------- bucket fill (scan3 fused) ----------------
__global__ void fill_kernel(const int* __restrict__ row, const int* __restrict__ col,
                            const int* __restrict__ offs,
                            const unsigned int* __restrict__ partial,
                            unsigned int* __restrict__ fillc,
                            int* __restrict__ bucket, int E) {
    int e = blockIdx.x * blockDim.x + threadIdx.x;
    if (e < E) {
        int c = col[e];
        unsigned int p = atomicAdd(&fillc[c], 1u);
        bucket[offs[c] + (int)partial[c >> 8] + (int)p] = row[e];
    }
}

// ---------------- aggregate: one wave per destination node ----------------
// out[c] = relu(dinv[c] * (sum_{r in bucket(c)} g[r] + g[c]) + bias)
// 16 lanes cover one 256B bf16 row (ushort8 per lane); 4 lane-groups -> 4 edges/iter.
__global__ void aggregate_kernel(const unsigned short* __restrict__ g,
                                 const int* __restrict__ bucket,
                                 const int* __restrict__ offs,
                                 const unsigned int* __restrict__ partial,
                                 const unsigned int* __restrict__ cnt,
                                 const float* __restrict__ dinv,
                                 const float* __restrict__ bias,
                                 float* __restrict__ out, int N) {
    int wid = threadIdx.x >> 6;
    int lane = threadIdx.x & 63;
    int c = blockIdx.x * 4 + wid;
    if (c >= N) return;
    int grp = lane >> 4;           // 0..3: which edge of the 4-batch
    int li = lane & 15;
    int col0 = li * 8;             // 8 bf16 columns per lane
    int start = offs[c] + (int)partial[c >> 8];
    int end = start + (int)cnt[c];

    float acc[8];
    if (grp == 0) {                // self-loop message
        short8 v = *(const short8*)(g + (size_t)c * NFEAT + col0);
        #pragma unroll
        for (int i = 0; i < 8; ++i) acc[i] = bf2f((unsigned short)v[i]);
    } else {
        #pragma unroll
        for (int i = 0; i < 8; ++i) acc[i] = 0.f;
    }

    for (int j = start; j < end; j += 4) {
        int jj = j + grp;
        if (jj < end) {
            int r = bucket[jj];
            short8 v = *(const short8*)(g + (size_t)r * NFEAT + col0);
            #pragma unroll
            for (int i = 0; i < 8; ++i) acc[i] += bf2f((unsigned short)v[i]);
        }
    }

    // reduce the 4 lane-groups (lanes with equal li hold the same columns)
    #pragma unroll
    for (int i = 0; i < 8; ++i) {
        acc[i] += __shfl_xor(acc[i], 16, 64);
        acc[i] += __shfl_xor(acc[i], 32, 64);
    }

    if (grp == 0) {
        float d = dinv[c];
        const float4* bp = (const float4*)(bias + col0);
        float4 b0 = bp[0], b1 = bp[1];
        float4 o0, o1;
        o0.x = fmaxf(acc[0] * d + b0.x, 0.f);
        o0.y = fmaxf(acc[1] * d + b0.y, 0.f);
        o0.z = fmaxf(acc[2] * d + b0.z, 0.f);
        o0.w = fmaxf(acc[3] * d + b0.w, 0.f);
        o1.x = fmaxf(acc[4] * d + b1.x, 0.f);
        o1.y = fmaxf(acc[5] * d + b1.y, 0.f);
        o1.z = fmaxf(acc[6] * d + b1.z, 0.f);
        o1.w = fmaxf(acc[7] * d + b1.w, 0.f);
        float4* op = (float4*)(out + (size_t)c * NFEAT + col0);
        op[0] = o0;
        op[1] = o1;
    }
}

extern "C" void kernel_launch(void* const* d_in, const int* in_sizes, int n_in,
                              void* d_out, int out_size, void* d_ws, size_t ws_size,
                              hipStream_t stream) {
    const float* x    = (const float*)d_in[0];
    const int*   ei   = (const int*)d_in[1];
    const float* W    = (const float*)d_in[2];
    const float* bias = (const float*)d_in[3];
    float* out = (float*)d_out;

    int N = in_sizes[0] / NFEAT;   // 50000
    int E = in_sizes[1] / 2;       // 800000
    const int* row = ei;           // sources
    const int* col = ei + E;       // destinations

    // ws: cnt[N] | dinv[N] | offs[N] | fillc[N] | partial[256] | Wt[128*128]bf16 | bucket[E] | g[N*128]bf16
    char* ws = (char*)d_ws;
    size_t o = 0;
    unsigned int*   cnt     = (unsigned int*)(ws + o);   o += (size_t)N * 4;
    float*          dinv    = (float*)(ws + o);          o += (size_t)N * 4;
    int*            offs    = (int*)(ws + o);            o += (size_t)N * 4;
    unsigned int*   fillc   = (unsigned int*)(ws + o);   o += (size_t)N * 4;
    unsigned int*   partial = (unsigned int*)(ws + o);   o += 1024;
    unsigned short* Wt      = (unsigned short*)(ws + o); o += (size_t)NFEAT * NFEAT * 2;
    int*            bucket  = (int*)(ws + o);            o += (size_t)E * 4;
    unsigned short* g       = (unsigned short*)(ws + o); // N*128 bf16

    int nb = (N + 255) / 256;   // 196 <= 256

    hipMemsetAsync(cnt, 0, (size_t)N * 4, stream);
    hipMemsetAsync(fillc, 0, (size_t)N * 4, stream);

    count_deg_kernel<<<(E + 255) / 256, 256, 0, stream>>>(col, E, cnt);
    scan1_kernel<<<nb, 256, 0, stream>>>(cnt, N, offs, partial, dinv);
    scan2_kernel<<<1, 256, 0, stream>>>(partial, nb);
    wprep_kernel<<<64, 256, 0, stream>>>(W, Wt);

    gemm_mfma_kernel<<<(N + 63) / 64, 256, 0, stream>>>(x, Wt, dinv, g, N);

    fill_kernel<<<(E + 255) / 256, 256, 0, stream>>>(row, col, offs, partial, fillc, bucket, E);

    aggregate_kernel<<<(N + 3) / 4, 256, 0, stream>>>(
        g, bucket, offs, partial, cnt, dinv, bias, out, N);
}

// Round 4
// 129.604 us; speedup vs baseline: 11.1580x; 1.1996x over previous
//
#include <hip/hip_runtime.h>

#define NFEAT 128

typedef __attribute__((ext_vector_type(8))) short short8;    // 8 bf16 (4 VGPRs)
typedef __attribute__((ext_vector_type(4))) float f32x4;     // MFMA accumulator

__device__ inline short f2bf(float f) {
    unsigned u = __builtin_bit_cast(unsigned, f);
    u += 0x7FFFu + ((u >> 16) & 1u);           // round-to-nearest-even
    return (short)(u >> 16);
}
__device__ inline float bf2f(unsigned short u) {
    return __builtin_bit_cast(float, ((unsigned)u) << 16);
}

// ---------------- prep: zero cnt + build Wt (bf16, transposed) ----------------
__global__ void prep_kernel(const float* __restrict__ W, unsigned short* __restrict__ Wt,
                            unsigned int* __restrict__ cnt, int N) {
    int i = blockIdx.x * 256 + threadIdx.x;
    if (i < N) cnt[i] = 0u;
    if (i < NFEAT * NFEAT) {
        int k = i >> 7, n = i & 127;
        Wt[n * NFEAT + k] = (unsigned short)f2bf(W[k * NFEAT + n]);
    }
}

// ---------------- count + ticket: cnt[col[e]]++, remember my slot ----------------
__global__ void count_ticket_kernel(const int* __restrict__ col, int E,
                                    unsigned int* __restrict__ cnt,
                                    int* __restrict__ eticket) {
    int i = blockIdx.x * blockDim.x + threadIdx.x;
    if (i < E) eticket[i] = (int)atomicAdd(&cnt[col[i]], 1u);
}

// ---------------- scan stage 1 (+ fused dinv) ----------------
__global__ void scan1_kernel(const unsigned int* __restrict__ cnt, int N,
                             int* __restrict__ offs, unsigned int* __restrict__ partial,
                             float* __restrict__ dinv) {
    __shared__ unsigned int s[256];
    int i = blockIdx.x * 256 + threadIdx.x;
    unsigned int v = (i < N) ? cnt[i] : 0u;
    if (i < N) dinv[i] = rsqrtf((float)(v + 1u));   // + self-loop
    s[threadIdx.x] = v;
    __syncthreads();
    for (int d = 1; d < 256; d <<= 1) {
        unsigned int t = (threadIdx.x >= d) ? s[threadIdx.x - d] : 0u;
        __syncthreads();
        s[threadIdx.x] += t;
        __syncthreads();
    }
    if (i < N) offs[i] = (int)(s[threadIdx.x] - v);   // exclusive within block
    if (threadIdx.x == 255) partial[blockIdx.x] = s[255];
}

// ---------------- scan stage 2: exclusive scan of block totals ----------------
__global__ void scan2_kernel(unsigned int* __restrict__ partial, int nb) {
    __shared__ unsigned int s[256];
    unsigned int v = (threadIdx.x < nb) ? partial[threadIdx.x] : 0u;
    s[threadIdx.x] = v;
    __syncthreads();
    for (int d = 1; d < 256; d <<= 1) {
        unsigned int t = (threadIdx.x >= d) ? s[threadIdx.x - d] : 0u;
        __syncthreads();
        s[threadIdx.x] += t;
        __syncthreads();
    }
    if (threadIdx.x < nb) partial[threadIdx.x] = s[threadIdx.x] - v;  // exclusive
}

// ---------------- g = bf16((x @ W) * dinv[row]) via MFMA ----------------
__global__ void gemm_mfma_kernel(const float* __restrict__ x,
                                 const unsigned short* __restrict__ Wt,
                                 const float* __restrict__ dinv,
                                 unsigned short* __restrict__ g, int N) {
    int wave = threadIdx.x >> 6;
    int lane = threadIdx.x & 63;
    int li = lane & 15;
    int kg = lane >> 4;                 // 0..3
    int m0 = blockIdx.x * 64 + wave * 16;
    int arow = m0 + li;
    int srow = (arow < N) ? arow : (N - 1);

    f32x4 acc[8];
    #pragma unroll
    for (int nt = 0; nt < 8; ++nt) acc[nt] = (f32x4){0.f, 0.f, 0.f, 0.f};

    #pragma unroll
    for (int ks = 0; ks < 4; ++ks) {
        const float4* xp = (const float4*)(x + (size_t)srow * NFEAT + ks * 32 + kg * 8);
        float4 f0 = xp[0], f1 = xp[1];
        short8 a;
        a[0] = f2bf(f0.x); a[1] = f2bf(f0.y); a[2] = f2bf(f0.z); a[3] = f2bf(f0.w);
        a[4] = f2bf(f1.x); a[5] = f2bf(f1.y); a[6] = f2bf(f1.z); a[7] = f2bf(f1.w);
        #pragma unroll
        for (int nt = 0; nt < 8; ++nt) {
            short8 b = *(const short8*)(Wt + (size_t)(nt * 16 + li) * NFEAT + ks * 32 + kg * 8);
            acc[nt] = __builtin_amdgcn_mfma_f32_16x16x32_bf16(a, b, acc[nt], 0, 0, 0);
        }
    }

    // D layout: col = nt*16 + (lane&15), row = m0 + kg*4 + r   [m89-verified]
    #pragma unroll
    for (int r = 0; r < 4; ++r) {
        int orow = m0 + kg * 4 + r;
        if (orow < N) {
            float dv = dinv[orow];
            unsigned short* gp = g + (size_t)orow * NFEAT + li;
            #pragma unroll
            for (int nt = 0; nt < 8; ++nt)
                gp[nt * 16] = (unsigned short)f2bf(acc[nt][r] * dv);
        }
    }
}

// ---------------- bucket fill: no atomics (ticket from count pass) ----------------
__global__ void fill_kernel(const int* __restrict__ row, const int* __restrict__ col,
                            const int* __restrict__ offs,
                            const unsigned int* __restrict__ partial,
                            const int* __restrict__ eticket,
                            int* __restrict__ bucket, int E) {
    int e = blockIdx.x * blockDim.x + threadIdx.x;
    if (e < E) {
        int c = col[e];
        bucket[offs[c] + (int)partial[c >> 8] + eticket[e]] = row[e];
    }
}

// ---------------- aggregate: one wave per destination node ----------------
// out[c] = relu(dinv[c] * (sum_{r in bucket(c)} g[r] + g[c]) + bias)
// 16 lanes cover one 256B bf16 row; 4 lane-groups x 2-deep unroll -> 8 edges/iter.
__global__ void aggregate_kernel(const unsigned short* __restrict__ g,
                                 const int* __restrict__ bucket,
                                 const int* __restrict__ offs,
                                 const unsigned int* __restrict__ partial,
                                 const unsigned int* __restrict__ cnt,
                                 const float* __restrict__ dinv,
                                 const float* __restrict__ bias,
                                 float* __restrict__ out, int N) {
    int wid = threadIdx.x >> 6;
    int lane = threadIdx.x & 63;
    int c = blockIdx.x * 4 + wid;
    if (c >= N) return;
    int grp = lane >> 4;           // 0..3
    int li = lane & 15;
    int col0 = li * 8;             // 8 bf16 columns per lane
    int start = offs[c] + (int)partial[c >> 8];
    int end = start + (int)cnt[c];

    float acc[8];
    if (grp == 0) {                // self-loop message
        short8 v = *(const short8*)(g + (size_t)c * NFEAT + col0);
        #pragma unroll
        for (int i = 0; i < 8; ++i) acc[i] = bf2f((unsigned short)v[i]);
    } else {
        #pragma unroll
        for (int i = 0; i < 8; ++i) acc[i] = 0.f;
    }

    for (int j = start; j < end; j += 8) {
        int jj0 = j + grp, jj1 = j + grp + 4;
        bool p0 = jj0 < end, p1 = jj1 < end;
        int r0 = p0 ? bucket[jj0] : 0;
        int r1 = p1 ? bucket[jj1] : 0;
        short8 v0, v1;
        if (p0) v0 = *(const short8*)(g + (size_t)r0 * NFEAT + col0);
        if (p1) v1 = *(const short8*)(g + (size_t)r1 * NFEAT + col0);
        if (p0) {
            #pragma unroll
            for (int i = 0; i < 8; ++i) acc[i] += bf2f((unsigned short)v0[i]);
        }
        if (p1) {
            #pragma unroll
            for (int i = 0; i < 8; ++i) acc[i] += bf2f((unsigned short)v1[i]);
        }
    }

    // reduce the 4 lane-groups
    #pragma unroll
    for (int i = 0; i < 8; ++i) {
        acc[i] += __shfl_xor(acc[i], 16, 64);
        acc[i] += __shfl_xor(acc[i], 32, 64);
    }

    if (grp == 0) {
        float d = dinv[c];
        const float4* bp = (const float4*)(bias + col0);
        float4 b0 = bp[0], b1 = bp[1];
        float4 o0, o1;
        o0.x = fmaxf(acc[0] * d + b0.x, 0.f);
        o0.y = fmaxf(acc[1] * d + b0.y, 0.f);
        o0.z = fmaxf(acc[2] * d + b0.z, 0.f);
        o0.w = fmaxf(acc[3] * d + b0.w, 0.f);
        o1.x = fmaxf(acc[4] * d + b1.x, 0.f);
        o1.y = fmaxf(acc[5] * d + b1.y, 0.f);
        o1.z = fmaxf(acc[6] * d + b1.z, 0.f);
        o1.w = fmaxf(acc[7] * d + b1.w, 0.f);
        float4* op = (float4*)(out + (size_t)c * NFEAT + col0);
        op[0] = o0;
        op[1] = o1;
    }
}

extern "C" void kernel_launch(void* const* d_in, const int* in_sizes, int n_in,
                              void* d_out, int out_size, void* d_ws, size_t ws_size,
                              hipStream_t stream) {
    const float* x    = (const float*)d_in[0];
    const int*   ei   = (const int*)d_in[1];
    const float* W    = (const float*)d_in[2];
    const float* bias = (const float*)d_in[3];
    float* out = (float*)d_out;

    int N = in_sizes[0] / NFEAT;   // 50000
    int E = in_sizes[1] / 2;       // 800000
    const int* row = ei;           // sources
    const int* col = ei + E;       // destinations

    // ws: cnt[N] | dinv[N] | offs[N] | partial[256] | Wt[128*128]bf16 | eticket[E] | bucket[E] | g[N*128]bf16
    char* ws = (char*)d_ws;
    size_t o = 0;
    unsigned int*   cnt     = (unsigned int*)(ws + o);   o += (size_t)N * 4;
    float*          dinv    = (float*)(ws + o);          o += (size_t)N * 4;
    int*            offs    = (int*)(ws + o);            o += (size_t)N * 4;
    unsigned int*   partial = (unsigned int*)(ws + o);   o += 1024;
    unsigned short* Wt      = (unsigned short*)(ws + o); o += (size_t)NFEAT * NFEAT * 2;
    int*            eticket = (int*)(ws + o);            o += (size_t)E * 4;
    int*            bucket  = (int*)(ws + o);            o += (size_t)E * 4;
    unsigned short* g       = (unsigned short*)(ws + o); // N*128 bf16

    int nb = (N + 255) / 256;   // 196 <= 256

    prep_kernel<<<nb, 256, 0, stream>>>(W, Wt, cnt, N);
    count_ticket_kernel<<<(E + 255) / 256, 256, 0, stream>>>(col, E, cnt, eticket);
    scan1_kernel<<<nb, 256, 0, stream>>>(cnt, N, offs, partial, dinv);
    scan2_kernel<<<1, 256, 0, stream>>>(partial, nb);

    gemm_mfma_kernel<<<(N + 63) / 64, 256, 0, stream>>>(x, Wt, dinv, g, N);

    fill_kernel<<<(E + 255) / 256, 256, 0, stream>>>(row, col, offs, partial, eticket, bucket, E);

    aggregate_kernel<<<(N + 3) / 4, 256, 0, stream>>>(
        g, bucket, offs, partial, cnt, dinv, bias, out, N);
}

// Round 6
// 128.136 us; speedup vs baseline: 11.2857x; 1.0115x over previous
//
#include <hip/hip_runtime.h>

#define NFEAT 128

typedef __attribute__((ext_vector_type(8))) short short8;    // 8 bf16 (4 VGPRs)
typedef __attribute__((ext_vector_type(4))) float f32x4;     // MFMA accumulator
typedef __attribute__((ext_vector_type(4))) float f32x4v;    // native float4 for NT builtins
typedef __attribute__((ext_vector_type(2))) float f32x2v;    // native float2 for NT builtins

__device__ inline short f2bf(float f) {
    unsigned u = __builtin_bit_cast(unsigned, f);
    u += 0x7FFFu + ((u >> 16) & 1u);           // round-to-nearest-even
    return (short)(u >> 16);
}
__device__ inline float bf2f(unsigned short u) {
    return __builtin_bit_cast(float, ((unsigned)u) << 16);
}

// ---------------- prep: zero cnt + build Wt (bf16, transposed) ----------------
__global__ void prep_kernel(const float* __restrict__ W, unsigned short* __restrict__ Wt,
                            unsigned int* __restrict__ cnt, int N) {
    int i = blockIdx.x * 256 + threadIdx.x;
    if (i < N) cnt[i] = 0u;
    if (i < NFEAT * NFEAT) {
        int k = i >> 7, n = i & 127;
        Wt[n * NFEAT + k] = (unsigned short)f2bf(W[k * NFEAT + n]);
    }
}

// ---------------- count + ticket: cnt[col[e]]++, remember my slot ----------------
__global__ void count_ticket_kernel(const int* __restrict__ col, int E,
                                    unsigned int* __restrict__ cnt,
                                    int* __restrict__ eticket) {
    int i = blockIdx.x * blockDim.x + threadIdx.x;
    if (i < E) eticket[i] = (int)atomicAdd(&cnt[col[i]], 1u);
}

// ---------------- scan stage 1 (+ fused dinv) ----------------
__global__ void scan1_kernel(const unsigned int* __restrict__ cnt, int N,
                             int* __restrict__ offs, unsigned int* __restrict__ partial,
                             float* __restrict__ dinv) {
    __shared__ unsigned int s[256];
    int i = blockIdx.x * 256 + threadIdx.x;
    unsigned int v = (i < N) ? cnt[i] : 0u;
    if (i < N) dinv[i] = rsqrtf((float)(v + 1u));   // + self-loop
    s[threadIdx.x] = v;
    __syncthreads();
    for (int d = 1; d < 256; d <<= 1) {
        unsigned int t = (threadIdx.x >= d) ? s[threadIdx.x - d] : 0u;
        __syncthreads();
        s[threadIdx.x] += t;
        __syncthreads();
    }
    if (i < N) offs[i] = (int)(s[threadIdx.x] - v);   // exclusive within block
    if (threadIdx.x == 255) partial[blockIdx.x] = s[255];
}

// ---------------- scan stage 2: exclusive scan of block totals ----------------
__global__ void scan2_kernel(unsigned int* __restrict__ partial, int nb) {
    __shared__ unsigned int s[256];
    unsigned int v = (threadIdx.x < nb) ? partial[threadIdx.x] : 0u;
    s[threadIdx.x] = v;
    __syncthreads();
    for (int d = 1; d < 256; d <<= 1) {
        unsigned int t = (threadIdx.x >= d) ? s[threadIdx.x - d] : 0u;
        __syncthreads();
        s[threadIdx.x] += t;
        __syncthreads();
    }
    if (threadIdx.x < nb) partial[threadIdx.x] = s[threadIdx.x] - v;  // exclusive
}

// ---------------- bucket fill: no atomics (ticket from count pass) ----------------
__global__ void fill_kernel(const int* __restrict__ row, const int* __restrict__ col,
                            const int* __restrict__ offs,
                            const unsigned int* __restrict__ partial,
                            const int* __restrict__ eticket,
                            int* __restrict__ bucket, int E) {
    int e = blockIdx.x * blockDim.x + threadIdx.x;
    if (e < E) {
        int c = col[e];
        bucket[offs[c] + (int)partial[c >> 8] + eticket[e]] = row[e];
    }
}

// ---------------- g = bf16((x @ W) * dinv[row]) via MFMA, LDS-repacked stores ----
__global__ void gemm_mfma_kernel(const float* __restrict__ x,
                                 const unsigned short* __restrict__ Wt,
                                 const float* __restrict__ dinv,
                                 unsigned short* __restrict__ g, int N) {
    __shared__ unsigned short tile[4][16][136];   // 272B row: 16B-aligned, kg 2-way banks
    int wave = threadIdx.x >> 6;
    int lane = threadIdx.x & 63;
    int li = lane & 15;
    int kg = lane >> 4;                 // 0..3
    int m0 = blockIdx.x * 64 + wave * 16;
    int arow = m0 + li;
    int srow = (arow < N) ? arow : (N - 1);

    f32x4 acc[8];
    #pragma unroll
    for (int nt = 0; nt < 8; ++nt) acc[nt] = (f32x4){0.f, 0.f, 0.f, 0.f};

    #pragma unroll
    for (int ks = 0; ks < 4; ++ks) {
        const f32x4v* xp = (const f32x4v*)(x + (size_t)srow * NFEAT + ks * 32 + kg * 8);
        f32x4v f0 = __builtin_nontemporal_load(xp);
        f32x4v f1 = __builtin_nontemporal_load(xp + 1);
        short8 a;
        a[0] = f2bf(f0.x); a[1] = f2bf(f0.y); a[2] = f2bf(f0.z); a[3] = f2bf(f0.w);
        a[4] = f2bf(f1.x); a[5] = f2bf(f1.y); a[6] = f2bf(f1.z); a[7] = f2bf(f1.w);
        #pragma unroll
        for (int nt = 0; nt < 8; ++nt) {
            short8 b = *(const short8*)(Wt + (size_t)(nt * 16 + li) * NFEAT + ks * 32 + kg * 8);
            acc[nt] = __builtin_amdgcn_mfma_f32_16x16x32_bf16(a, b, acc[nt], 0, 0, 0);
        }
    }

    // D layout: col = nt*16 + li, row = kg*4 + r  [m89] -> scale, repack via LDS
    #pragma unroll
    for (int r = 0; r < 4; ++r) {
        int orow = m0 + kg * 4 + r;
        float dv = (orow < N) ? dinv[orow] : 0.f;
        #pragma unroll
        for (int nt = 0; nt < 8; ++nt)
            tile[wave][kg * 4 + r][nt * 16 + li] = (unsigned short)f2bf(acc[nt][r] * dv);
    }
    __syncthreads();

    // coalesced store: 4 lanes cover 64B contiguous per row
    int row = lane >> 2;
    int orow = m0 + row;
    #pragma unroll
    for (int cc = 0; cc < 4; ++cc) {
        int chunk = cc * 4 + (lane & 3);          // 16B chunk index within the row
        if (orow < N) {
            short8 v = *(const short8*)&tile[wave][row][chunk * 8];
            *(short8*)(g + (size_t)orow * NFEAT + chunk * 8) = v;
        }
    }
}

// ---------------- aggregate: one wave per destination node ----------------
// out[c] = relu(dinv[c] * (sum_{r in bucket(c)} g[r] + g[c]) + bias)
// 16 lanes cover one 256B bf16 row; 4 lane-groups x 4-deep unroll -> 16 edges in flight.
__global__ void aggregate_kernel(const unsigned short* __restrict__ g,
                                 const int* __restrict__ bucket,
                                 const int* __restrict__ offs,
                                 const unsigned int* __restrict__ partial,
                                 const unsigned int* __restrict__ cnt,
                                 const float* __restrict__ dinv,
                                 const float* __restrict__ bias,
                                 float* __restrict__ out, int N) {
    int wid = threadIdx.x >> 6;
    int lane = threadIdx.x & 63;
    int c = blockIdx.x * 4 + wid;
    if (c >= N) return;
    int grp = lane >> 4;           // 0..3
    int li = lane & 15;
    int col0 = li * 8;             // 8 bf16 columns per lane
    int start = offs[c] + (int)partial[c >> 8];
    int end = start + (int)cnt[c];

    float acc[8];
    if (grp == 0) {                // self-loop message
        short8 v = *(const short8*)(g + (size_t)c * NFEAT + col0);
        #pragma unroll
        for (int i = 0; i < 8; ++i) acc[i] = bf2f((unsigned short)v[i]);
    } else {
        #pragma unroll
        for (int i = 0; i < 8; ++i) acc[i] = 0.f;
    }

    for (int j = start; j < end; j += 16) {
        int idx[4];
        bool p[4];
        short8 v[4];
        #pragma unroll
        for (int k = 0; k < 4; ++k) {
            int jj = j + grp + k * 4;
            p[k] = jj < end;
            idx[k] = p[k] ? bucket[jj] : 0;
        }
        #pragma unroll
        for (int k = 0; k < 4; ++k)
            if (p[k]) v[k] = *(const short8*)(g + (size_t)idx[k] * NFEAT + col0);
        #pragma unroll
        for (int k = 0; k < 4; ++k) {
            if (p[k]) {
                #pragma unroll
                for (int i = 0; i < 8; ++i) acc[i] += bf2f((unsigned short)v[k][i]);
            }
        }
    }

    // reduce the 4 lane-groups: afterwards every lane holds the full sums
    #pragma unroll
    for (int i = 0; i < 8; ++i) {
        acc[i] += __shfl_xor(acc[i], 16, 64);
        acc[i] += __shfl_xor(acc[i], 32, 64);
    }

    // distributed write: lane writes cols [col0 + grp*2, col0 + grp*2 + 1]
    float a0, a1;
    switch (grp) {
        case 0: a0 = acc[0]; a1 = acc[1]; break;
        case 1: a0 = acc[2]; a1 = acc[3]; break;
        case 2: a0 = acc[4]; a1 = acc[5]; break;
        default: a0 = acc[6]; a1 = acc[7]; break;
    }
    float d = dinv[c];
    const float2* bp = (const float2*)(bias + col0 + grp * 2);
    float2 b = *bp;
    f32x2v o;
    o.x = fmaxf(a0 * d + b.x, 0.f);
    o.y = fmaxf(a1 * d + b.y, 0.f);
    __builtin_nontemporal_store(o, (f32x2v*)(out + (size_t)c * NFEAT + col0 + grp * 2));
}

extern "C" void kernel_launch(void* const* d_in, const int* in_sizes, int n_in,
                              void* d_out, int out_size, void* d_ws, size_t ws_size,
                              hipStream_t stream) {
    const float* x    = (const float*)d_in[0];
    const int*   ei   = (const int*)d_in[1];
    const float* W    = (const float*)d_in[2];
    const float* bias = (const float*)d_in[3];
    float* out = (float*)d_out;

    int N = in_sizes[0] / NFEAT;   // 50000
    int E = in_sizes[1] / 2;       // 800000
    const int* row = ei;           // sources
    const int* col = ei + E;       // destinations

    // ws: cnt[N] | dinv[N] | offs[N] | partial[256] | Wt[128*128]bf16 | eticket[E] | bucket[E] | g[N*128]bf16
    char* ws = (char*)d_ws;
    size_t o = 0;
    unsigned int*   cnt     = (unsigned int*)(ws + o);   o += (size_t)N * 4;
    float*          dinv    = (float*)(ws + o);          o += (size_t)N * 4;
    int*            offs    = (int*)(ws + o);            o += (size_t)N * 4;
    unsigned int*   partial = (unsigned int*)(ws + o);   o += 1024;
    unsigned short* Wt      = (unsigned short*)(ws + o); o += (size_t)NFEAT * NFEAT * 2;
    int*            eticket = (int*)(ws + o);            o += (size_t)E * 4;
    int*            bucket  = (int*)(ws + o);            o += (size_t)E * 4;
    unsigned short* g       = (unsigned short*)(ws + o); // N*128 bf16

    int nb = (N + 255) / 256;   // 196 <= 256

    prep_kernel<<<nb, 256, 0, stream>>>(W, Wt, cnt, N);
    count_ticket_kernel<<<(E + 255) / 256, 256, 0, stream>>>(col, E, cnt, eticket);
    scan1_kernel<<<nb, 256, 0, stream>>>(cnt, N, offs, partial, dinv);
    scan2_kernel<<<1, 256, 0, stream>>>(partial, nb);

    // fill before gemm: keeps g hottest in L2 for aggregate
    fill_kernel<<<(E + 255) / 256, 256, 0, stream>>>(row, col, offs, partial, eticket, bucket, E);

    gemm_mfma_kernel<<<(N + 63) / 64, 256, 0, stream>>>(x, Wt, dinv, g, N);

    aggregate_kernel<<<(N + 3) / 4, 256, 0, stream>>>(
        g, bucket, offs, partial, cnt, dinv, bias, out, N);
}